// Round 6
// baseline (12056.182 us; speedup 1.0000x reference)
//
#include <hip/hip_runtime.h>

typedef unsigned short u16;
typedef unsigned char u8;
typedef unsigned int u32;

#define NSYM 512

// ---------------------------------------------------------------------------
// Build u16 copies of the luts, fused relu(add) table, and packed u8+bitplane
// copy of the add table (9 bits/entry) for LDS residency.
// ---------------------------------------------------------------------------
__global__ void build_tables_kernel(const int* __restrict__ conv_i,
                                    const int* __restrict__ add_i,
                                    const int* __restrict__ relu_i,
                                    u16* __restrict__ conv_u,
                                    u16* __restrict__ add_u,
                                    u16* __restrict__ addrelu_u,
                                    u8* __restrict__ u8g) {
    int i = blockIdx.x * blockDim.x + threadIdx.x;
    if (i < NSYM * NSYM) {
        conv_u[i] = (u16)conv_i[i];
        int a = add_i[i];
        add_u[i] = (u16)a;
        addrelu_u[i] = (u16)relu_i[a];
        u8g[i] = (u8)(a & 0xFF);
    }
}

__global__ void build_bitplane_kernel(const int* __restrict__ add_i,
                                      u32* __restrict__ bpg) {
    int w = blockIdx.x * blockDim.x + threadIdx.x;  // word id: 512 rows * 16 words
    if (w < NSYM * 16) {
        int c = w >> 4;
        int m0 = (w & 15) << 5;
        u32 b = 0;
        for (int k = 0; k < 32; ++k)
            b |= (u32)((add_i[(c << 9) + m0 + k] >> 8) & 1) << k;
        bpg[w] = b;
    }
}

// ---------------------------------------------------------------------------
// Quantize: argmin over sorted centroids == binary search + neighbor compare.
// Output layout: (img, y, x, ch), ch fastest.
// ---------------------------------------------------------------------------
__global__ void quantize_kernel(const float* __restrict__ x,
                                u16* __restrict__ s0,
                                const float* __restrict__ cent,
                                int n) {
    __shared__ float c[NSYM];
    for (int t = threadIdx.x; t < NSYM; t += blockDim.x) c[t] = cent[t];
    __syncthreads();
    int i = blockIdx.x * blockDim.x + threadIdx.x;
    if (i >= n) return;
    int ch = i % 3; int t2 = i / 3; int xx = t2 % 67; int t3 = t2 / 67;
    int y = t3 % 67; int img = t3 / 67;
    float v = x[((img * 3 + ch) * 67 + y) * 67 + xx];
    int lo = 0, hi = NSYM;
    while (lo < hi) { int mid = (lo + hi) >> 1; if (c[mid] < v) lo = mid + 1; else hi = mid; }
    int idx;
    if (lo == 0) idx = 0;
    else if (lo == NSYM) idx = NSYM - 1;
    else {
        float d1 = v - c[lo - 1];
        float d2 = v - c[lo];
        idx = (d1 * d1 <= d2 * d2) ? (lo - 1) : lo;
    }
    s0[i] = (u16)idx;
}

// ---------------------------------------------------------------------------
// Symbolic conv layer — fat-block version.
//   grid = 256 blocks (1 per CU), 1024 threads.
//   Block b owns chains [b*X, (b+1)*X) ordered as g = pix*OC + oc.
//   LDS: [u8 add-table LROWS*512][bitplane LROWS*64B][patches pixels_pb*J].
//   Chain step: carry < LROWS -> 2 LDS reads (u8 + bit) ; else global u16.
//   LROWS>0 only for throughput-bound layers (L0-L8); deep layers LROWS=0
//   (latency-bound: >=1 global lane per wave-step means no latency win).
//   m_j = conv[patch_j, W[j,oc]] prefetched depth-3 (independent loads).
// ---------------------------------------------------------------------------
__global__ __launch_bounds__(1024) void symconv_kernel(
        const u16* __restrict__ in, u16* __restrict__ out,
        const int* __restrict__ Wl,
        const u16* __restrict__ conv,
        const u16* __restrict__ addt,
        const u16* __restrict__ addlast,
        const u8* __restrict__ u8g,
        const u32* __restrict__ bpg,
        int H, int C, int OC,
        int K, int ST, int PAD, int OH, int OW,
        int X, int LROWS, int pixels_pb) {
    extern __shared__ char lds[];
    u8* u8tab = (u8*)lds;
    u32* bp = (u32*)(lds + (LROWS << 9));
    u16* patch = (u16*)(lds + LROWS * 576);
    int J = K * K * C;
    int tid = threadIdx.x;
    int g0 = blockIdx.x * X;
    int pixel0 = g0 / OC;

    // stage packed add table (coalesced u32 copies)
    if (LROWS > 0) {
        const u32* s8 = (const u32*)u8g;
        u32* d8 = (u32*)lds;
        int n8 = LROWS << 7;                    // LROWS*512/4
        for (int t = tid; t < n8; t += 1024) d8[t] = s8[t];
        int nb = LROWS << 4;                    // LROWS*64/4
        for (int t = tid; t < nb; t += 1024) bp[t] = bpg[t];
    }

    // stage patches; j order = (kr, kc, c), c fastest
    int np = pixels_pb * J;
    for (int t = tid; t < np; t += 1024) {
        int p = t / J; int j = t - p * J;
        int c = j % C; int tt = j / C; int kc = tt % K; int kr = tt / K;
        int pix = pixel0 + p;
        int img = pix / (OH * OW); int rem = pix - img * (OH * OW);
        int oy = rem / OW; int ox = rem - oy * OW;
        int iy = oy * ST + kr - PAD;
        int ix = ox * ST + kc - PAD;
        u16 v = 0;  // jnp.pad pads with symbol 0
        if (iy >= 0 && iy < H && ix >= 0 && ix < H)
            v = in[((img * H + iy) * H + ix) * C + c];
        patch[t] = v;
    }
    __syncthreads();

    if (tid >= X) return;
    int g = g0 + tid;
    int oc = g % OC;
    int pp = g / OC - pixel0;
    const u16* pat = patch + pp * J;

    auto ADDMIX = [&](int c2, int m) -> int {
        if (c2 < LROWS) {
            int lo = (int)u8tab[(c2 << 9) + m];
            int hi = (int)((bp[(c2 << 4) + (m >> 5)] >> (m & 31)) & 1);
            return lo | (hi << 8);
        }
        return (int)addt[(c2 << 9) + m];
    };
#define GM(j) ((int)conv[((int)pat[(j)] << 9) + Wl[(j) * OC + oc]])

    int carry = GM(0);
    int mA = GM(1);
    int mB = GM(2);
    int mC = GM(3);
    for (int j = 1; j < J - 3; ++j) {
        int mcur = mA; mA = mB; mB = mC;
        mC = GM(j + 3);
        carry = ADDMIX(carry, mcur);
    }
    carry = ADDMIX(carry, mA);
    carry = ADDMIX(carry, mB);
    carry = (int)addlast[(carry << 9) + mC];   // fused relu on relu layers
    out[g] = (u16)carry;
#undef GM
}

// ---------------------------------------------------------------------------
// Head: vals = centroid[s]; feats = mean over 2x2; out = feats @ fc_w.T + fc_b
// ---------------------------------------------------------------------------
__global__ void head_kernel(const u16* __restrict__ s,
                            const float* __restrict__ cent,
                            const float* __restrict__ fcw,
                            const float* __restrict__ fcb,
                            float* __restrict__ out) {
    __shared__ float feats[NSYM];
    int img = blockIdx.x;
    const u16* sp = s + img * 4 * NSYM;
    for (int c = threadIdx.x; c < NSYM; c += blockDim.x) {
        float acc = cent[sp[c]] + cent[sp[NSYM + c]] +
                    cent[sp[2 * NSYM + c]] + cent[sp[3 * NSYM + c]];
        feats[c] = acc * 0.25f;
    }
    __syncthreads();
    int o = blockIdx.y * blockDim.x + threadIdx.x;
    if (o < 1000) {
        float acc = fcb[o];
        const float* wr = fcw + o * NSYM;
        for (int c2 = 0; c2 < NSYM; ++c2) acc += feats[c2] * wr[c2];
        out[img * 1000 + o] = acc;
    }
}

// ---------------------------------------------------------------------------
extern "C" void kernel_launch(void* const* d_in, const int* in_sizes, int n_in,
                              void* d_out, int out_size, void* d_ws, size_t ws_size,
                              hipStream_t stream) {
    const float* x = (const float*)d_in[0];
    const int* w[17];
    for (int i = 0; i < 17; ++i) w[i] = (const int*)d_in[1 + i];
    const int* conv_i = (const int*)d_in[18];
    const int* add_i  = (const int*)d_in[19];
    const int* relu_i = (const int*)d_in[20];
    const float* cent = (const float*)d_in[21];
    const float* fcw  = (const float*)d_in[22];
    const float* fcb  = (const float*)d_in[23];
    float* out = (float*)d_out;

    char* p = (char*)d_ws;
    u16* conv_u    = (u16*)p; p += NSYM * NSYM * 2;
    u16* add_u     = (u16*)p; p += NSYM * NSYM * 2;
    u16* addrelu_u = (u16*)p; p += NSYM * NSYM * 2;
    u8*  u8g       = (u8*)p;  p += NSYM * NSYM;
    u32* bpg       = (u32*)p; p += NSYM * 16 * 4;
    u16* act0      = (u16*)p; p += ((8 * 67 * 67 * 3 * 2 + 255) / 256) * 256;
    u16* actA      = (u16*)p; p += 8 * 16 * 16 * 64 * 2;
    u16* actB      = (u16*)p; p += 8 * 16 * 16 * 64 * 2;

    build_tables_kernel<<<(NSYM * NSYM + 255) / 256, 256, 0, stream>>>(
        conv_i, add_i, relu_i, conv_u, add_u, addrelu_u, u8g);
    build_bitplane_kernel<<<(NSYM * 16 + 255) / 256, 256, 0, stream>>>(add_i, bpg);

    int nq = 8 * 67 * 67 * 3;
    quantize_kernel<<<(nq + 255) / 256, 256, 0, stream>>>(x, act0, cent, nq);

    struct LC { int K, ST, PAD, C, OC, H, OH, relu; };
    static const LC L[17] = {
        {7,4,0,  3, 64,67,16,1},
        {3,1,1, 64, 64,16,16,1},
        {3,1,1, 64, 64,16,16,0},
        {3,1,1, 64, 64,16,16,1},
        {3,1,1, 64, 64,16,16,0},
        {3,2,1, 64,128,16, 8,1},
        {3,1,1,128,128, 8, 8,0},
        {3,1,1,128,128, 8, 8,1},
        {3,1,1,128,128, 8, 8,0},
        {3,2,1,128,256, 8, 4,1},
        {3,1,1,256,256, 4, 4,0},
        {3,1,1,256,256, 4, 4,1},
        {3,1,1,256,256, 4, 4,0},
        {3,2,1,256,512, 4, 2,1},
        {3,1,1,512,512, 2, 2,0},
        {3,1,1,512,512, 2, 2,1},
        {3,1,1,512,512, 2, 2,0},
    };

    // Precompute per-layer geometry + LROWS; find max LDS for the attribute.
    int Xs[17], ppb[17], lrows[17], ldsb[17];
    int maxlds = 0;
    for (int i = 0; i < 17; ++i) {
        int OH = L[i].OH;
        int chains = 8 * OH * OH * L[i].OC;
        int X = chains / 256;
        int J = L[i].K * L[i].K * L[i].C;
        int pb = (X >= L[i].OC) ? (X / L[i].OC) : 1;
        int patchB = pb * J * 2;
        int lr = 0;
        if (i <= 8) {                      // throughput-bound layers only
            lr = (163840 - patchB) / 576;
            if (lr > NSYM) lr = NSYM;
        }
        Xs[i] = X; ppb[i] = pb; lrows[i] = lr;
        ldsb[i] = lr * 576 + patchB;
        if (ldsb[i] > maxlds) maxlds = ldsb[i];
    }
    // Allow >64KB dynamic LDS (host-side config; idempotent; not captured).
    hipFuncSetAttribute((const void*)symconv_kernel,
                        hipFuncAttributeMaxDynamicSharedMemorySize, maxlds);

    const u16* cur = act0;
    u16* nxt = actA;
    for (int i = 0; i < 17; ++i) {
        symconv_kernel<<<256, 1024, ldsb[i], stream>>>(
            cur, nxt, w[i], conv_u, add_u, L[i].relu ? addrelu_u : add_u,
            u8g, bpg,
            L[i].H, L[i].C, L[i].OC,
            L[i].K, L[i].ST, L[i].PAD, L[i].OH, L[i].OH,
            Xs[i], lrows[i], ppb[i]);
        cur = nxt;
        nxt = (nxt == actA) ? actB : actA;
    }

    head_kernel<<<dim3(8, 4), 256, 0, stream>>>(cur, cent, fcw, fcb, out);
}

// Round 8
// 6661.389 us; speedup vs baseline: 1.8099x; 1.8099x over previous
//
#include <hip/hip_runtime.h>

typedef unsigned short u16;

#define NSYM 512

// ---------------------------------------------------------------------------
// Build u16 copies of the luts + fused relu(add_lut) table
// ---------------------------------------------------------------------------
__global__ void build_tables_kernel(const int* __restrict__ conv_i,
                                    const int* __restrict__ add_i,
                                    const int* __restrict__ relu_i,
                                    u16* __restrict__ conv_u,
                                    u16* __restrict__ add_u,
                                    u16* __restrict__ addrelu_u) {
    int i = blockIdx.x * blockDim.x + threadIdx.x;
    if (i < NSYM * NSYM) {
        conv_u[i] = (u16)conv_i[i];
        int a = add_i[i];
        add_u[i] = (u16)a;
        addrelu_u[i] = (u16)relu_i[a];
    }
}

// ---------------------------------------------------------------------------
// Quantize: argmin over sorted centroids == binary search + neighbor compare.
// Output layout: (img, y, x, ch), ch fastest.
// ---------------------------------------------------------------------------
__global__ void quantize_kernel(const float* __restrict__ x,
                                u16* __restrict__ s0,
                                const float* __restrict__ cent,
                                int n) {
    __shared__ float c[NSYM];
    for (int t = threadIdx.x; t < NSYM; t += blockDim.x) c[t] = cent[t];
    __syncthreads();
    int i = blockIdx.x * blockDim.x + threadIdx.x;
    if (i >= n) return;
    int ch = i % 3; int t2 = i / 3; int xx = t2 % 67; int t3 = t2 / 67;
    int y = t3 % 67; int img = t3 / 67;
    float v = x[((img * 3 + ch) * 67 + y) * 67 + xx];
    int lo = 0, hi = NSYM;
    while (lo < hi) { int mid = (lo + hi) >> 1; if (c[mid] < v) lo = mid + 1; else hi = mid; }
    int idx;
    if (lo == 0) idx = 0;
    else if (lo == NSYM) idx = NSYM - 1;
    else {
        float d1 = v - c[lo - 1];
        float d2 = v - c[lo];
        idx = (d1 * d1 <= d2 * d2) ? (lo - 1) : lo;
    }
    s0[i] = (u16)idx;
}

// ---------------------------------------------------------------------------
// LDS-W symbolic conv (layers with J*128B <= ~150KB, i.e. L0..L9).
//   Block = PPB pixels x one 64-oc group = PPB waves; wave w owns pixel w,
//   lane = oc within group. W slice (J x 64 u16) staged in LDS once ->
//   removes the per-step Wl global load (TA 192 -> 128 lanes/step).
//   Steady state: W_lds read = 2 lanes/bank (free), patch read = wave-uniform
//   broadcast (free). conv + addt stay global gathers; depth-3 m prefetch.
// ---------------------------------------------------------------------------
__global__ __launch_bounds__(512) void symconv_ldsw_kernel(
        const u16* __restrict__ in, u16* __restrict__ out,
        const int* __restrict__ Wl,
        const u16* __restrict__ conv,
        const u16* __restrict__ addt,
        const u16* __restrict__ addlast,
        int H, int C, int OC, int nOCG,
        int K, int ST, int PAD, int OH, int OW, int PPB) {
    extern __shared__ u16 lds[];
    int J = K * K * C;
    u16* wlds = lds;            // J*64
    u16* patch = lds + J * 64;  // PPB*J

    int bid = blockIdx.x;
    int ocg = bid % nOCG;
    int pblk = bid / nOCG;
    int pixel0 = pblk * PPB;
    int tid = threadIdx.x;
    int nthr = PPB << 6;

    // stage W slice: wlds[j*64 + oc'] = Wl[j*OC + ocg*64 + oc']  (coalesced)
    for (int t = tid; t < J * 64; t += nthr) {
        int j = t >> 6; int ocp = t & 63;
        wlds[t] = (u16)Wl[j * OC + (ocg << 6) + ocp];
    }
    // stage patches; j order = (kr, kc, c), c fastest
    for (int t = tid; t < PPB * J; t += nthr) {
        int p = t / J; int j = t - p * J;
        int c = j % C; int tt = j / C; int kc = tt % K; int kr = tt / K;
        int pix = pixel0 + p;
        int img = pix / (OH * OW); int rem = pix - img * (OH * OW);
        int oy = rem / OW; int ox = rem - oy * OW;
        int iy = oy * ST + kr - PAD;
        int ix = ox * ST + kc - PAD;
        u16 v = 0;  // jnp.pad pads with symbol 0
        if (iy >= 0 && iy < H && ix >= 0 && ix < H)
            v = in[((img * H + iy) * H + ix) * C + c];
        patch[p * J + j] = v;
    }
    __syncthreads();

    int wave = tid >> 6;
    int lane = tid & 63;
    int pix = pixel0 + wave;
    const u16* pat = patch + wave * J;

#define GM(j) ((int)conv[((int)pat[(j)] << 9) + (int)wlds[((j) << 6) + lane]])

    int carry = GM(0);
    int mA = GM(1);
    int mB = GM(2);
    int mC = GM(3);
    for (int j = 1; j < J - 3; ++j) {
        int mcur = mA; mA = mB; mB = mC;
        mC = GM(j + 3);
        carry = (int)addt[(carry << 9) + mcur];
    }
    carry = (int)addt[(carry << 9) + mA];
    carry = (int)addt[(carry << 9) + mB];
    carry = (int)addlast[(carry << 9) + mC];
    out[pix * OC + (ocg << 6) + lane] = (u16)carry;
#undef GM
}

// ---------------------------------------------------------------------------
// Global-W symbolic conv (deep layers L10..L16; latency-bound, TA idle).
// Identical to the round-2 kernel: 64-thread blocks, one pixel x 64 oc.
// ---------------------------------------------------------------------------
__global__ __launch_bounds__(64) void symconv_glob_kernel(
        const u16* __restrict__ in, u16* __restrict__ out,
        const int* __restrict__ Wl,
        const u16* __restrict__ conv,
        const u16* __restrict__ addt,
        const u16* __restrict__ addlast,
        int H, int C, int OC, int nOCG,
        int K, int ST, int PAD, int OH, int OW) {
    extern __shared__ u16 patch[];
    int bid = blockIdx.x;
    int ocg = bid % nOCG;
    int pix = bid / nOCG;
    int img = pix / (OH * OW);
    int rem = pix - img * (OH * OW);
    int oy = rem / OW;
    int ox = rem - oy * OW;
    int J = K * K * C;
    for (int t = threadIdx.x; t < J; t += 64) {
        int c = t % C; int tt = t / C; int kc = tt % K; int kr = tt / K;
        int iy = oy * ST + kr - PAD;
        int ix = ox * ST + kc - PAD;
        u16 v = 0;
        if (iy >= 0 && iy < H && ix >= 0 && ix < H)
            v = in[((img * H + iy) * H + ix) * C + c];
        patch[t] = v;
    }
    __syncthreads();
    int oc = (ocg << 6) + threadIdx.x;

#define GM(j) ((int)conv[((int)patch[(j)] << 9) + Wl[(j) * OC + oc]])

    int carry = GM(0);
    int mA = GM(1);
    int mB = GM(2);
    int mC = GM(3);
    for (int j = 1; j < J - 3; ++j) {
        int mcur = mA; mA = mB; mB = mC;
        mC = GM(j + 3);
        carry = (int)addt[(carry << 9) + mcur];
    }
    carry = (int)addt[(carry << 9) + mA];
    carry = (int)addt[(carry << 9) + mB];
    carry = (int)addlast[(carry << 9) + mC];
    out[pix * OC + oc] = (u16)carry;
#undef GM
}

// ---------------------------------------------------------------------------
// Head: vals = centroid[s]; feats = mean over 2x2; out = feats @ fc_w.T + fc_b
// ---------------------------------------------------------------------------
__global__ void head_kernel(const u16* __restrict__ s,
                            const float* __restrict__ cent,
                            const float* __restrict__ fcw,
                            const float* __restrict__ fcb,
                            float* __restrict__ out) {
    __shared__ float feats[NSYM];
    int img = blockIdx.x;
    const u16* sp = s + img * 4 * NSYM;
    for (int c = threadIdx.x; c < NSYM; c += blockDim.x) {
        float acc = cent[sp[c]] + cent[sp[NSYM + c]] +
                    cent[sp[2 * NSYM + c]] + cent[sp[3 * NSYM + c]];
        feats[c] = acc * 0.25f;
    }
    __syncthreads();
    int o = blockIdx.y * blockDim.x + threadIdx.x;
    if (o < 1000) {
        float acc = fcb[o];
        const float* wr = fcw + o * NSYM;
        for (int c2 = 0; c2 < NSYM; ++c2) acc += feats[c2] * wr[c2];
        out[img * 1000 + o] = acc;
    }
}

// ---------------------------------------------------------------------------
extern "C" void kernel_launch(void* const* d_in, const int* in_sizes, int n_in,
                              void* d_out, int out_size, void* d_ws, size_t ws_size,
                              hipStream_t stream) {
    const float* x = (const float*)d_in[0];
    const int* w[17];
    for (int i = 0; i < 17; ++i) w[i] = (const int*)d_in[1 + i];
    const int* conv_i = (const int*)d_in[18];
    const int* add_i  = (const int*)d_in[19];
    const int* relu_i = (const int*)d_in[20];
    const float* cent = (const float*)d_in[21];
    const float* fcw  = (const float*)d_in[22];
    const float* fcb  = (const float*)d_in[23];
    float* out = (float*)d_out;

    char* p = (char*)d_ws;
    u16* conv_u    = (u16*)p; p += NSYM * NSYM * 2;
    u16* add_u     = (u16*)p; p += NSYM * NSYM * 2;
    u16* addrelu_u = (u16*)p; p += NSYM * NSYM * 2;
    u16* act0      = (u16*)p; p += ((8 * 67 * 67 * 3 * 2 + 255) / 256) * 256;
    u16* actA      = (u16*)p; p += 8 * 16 * 16 * 64 * 2;
    u16* actB      = (u16*)p; p += 8 * 16 * 16 * 64 * 2;

    build_tables_kernel<<<(NSYM * NSYM + 255) / 256, 256, 0, stream>>>(
        conv_i, add_i, relu_i, conv_u, add_u, addrelu_u);

    int nq = 8 * 67 * 67 * 3;
    quantize_kernel<<<(nq + 255) / 256, 256, 0, stream>>>(x, act0, cent, nq);

    struct LC { int K, ST, PAD, C, OC, H, OH, relu, PPB; };
    // PPB>0 -> LDS-W kernel (PPB pixels/block); PPB=0 -> global-W kernel.
    static const LC L[17] = {
        {7,4,0,  3, 64,67,16,1, 8},
        {3,1,1, 64, 64,16,16,1, 8},
        {3,1,1, 64, 64,16,16,0, 8},
        {3,1,1, 64, 64,16,16,1, 8},
        {3,1,1, 64, 64,16,16,0, 8},
        {3,2,1, 64,128,16, 8,1, 4},
        {3,1,1,128,128, 8, 8,0, 4},
        {3,1,1,128,128, 8, 8,1, 4},
        {3,1,1,128,128, 8, 8,0, 4},
        {3,2,1,128,256, 8, 4,1, 2},
        {3,1,1,256,256, 4, 4,0, 0},
        {3,1,1,256,256, 4, 4,1, 0},
        {3,1,1,256,256, 4, 4,0, 0},
        {3,2,1,256,512, 4, 2,1, 0},
        {3,1,1,512,512, 2, 2,0, 0},
        {3,1,1,512,512, 2, 2,1, 0},
        {3,1,1,512,512, 2, 2,0, 0},
    };

    // Max dynamic LDS for the LDS-W kernel (L6-8: 1152*128 + 4*1152*2 bytes).
    int maxlds = 0;
    for (int i = 0; i < 17; ++i) {
        if (L[i].PPB > 0) {
            int J = L[i].K * L[i].K * L[i].C;
            int b = J * 64 * 2 + L[i].PPB * J * 2;
            if (b > maxlds) maxlds = b;
        }
    }
    hipFuncSetAttribute((const void*)symconv_ldsw_kernel,
                        hipFuncAttributeMaxDynamicSharedMemorySize, maxlds);

    const u16* cur = act0;
    u16* nxt = actA;
    for (int i = 0; i < 17; ++i) {
        int OH = L[i].OH;
        int nOCG = L[i].OC / 64;
        int J = L[i].K * L[i].K * L[i].C;
        const u16* lastt = L[i].relu ? addrelu_u : add_u;
        if (L[i].PPB > 0) {
            int PPB = L[i].PPB;
            int pixels = 8 * OH * OH;
            int grid = (pixels / PPB) * nOCG;
            int ldsB = J * 64 * 2 + PPB * J * 2;
            symconv_ldsw_kernel<<<grid, PPB * 64, ldsB, stream>>>(
                cur, nxt, w[i], conv_u, add_u, lastt,
                L[i].H, L[i].C, L[i].OC, nOCG,
                L[i].K, L[i].ST, L[i].PAD, OH, OH, PPB);
        } else {
            int grid = 8 * OH * OH * nOCG;
            symconv_glob_kernel<<<grid, 64, J * 2, stream>>>(
                cur, nxt, w[i], conv_u, add_u, lastt,
                L[i].H, L[i].C, L[i].OC, nOCG,
                L[i].K, L[i].ST, L[i].PAD, OH, OH);
        }
        cur = nxt;
        nxt = (nxt == actA) ? actB : actA;
    }

    head_kernel<<<dim3(8, 4), 256, 0, stream>>>(cur, cent, fcw, fcb, out);
}